// Round 15
// baseline (6963.866 us; speedup 1.0000x reference)
//
#include <hip/hip_runtime.h>
#include <hip/hip_fp16.h>

#define HDIM 256
#define LSEQ 512
#define PRED 96

typedef _Float16 f16x8 __attribute__((ext_vector_type(8)));
typedef float f32x4 __attribute__((ext_vector_type(4)));

__device__ __forceinline__ float sigm(float x) { return 1.f / (1.f + __expf(-x)); }
__device__ __forceinline__ float tanh_(float x) { float t = __expf(2.f * x); return 1.f - 2.f / (t + 1.f); }

// load 8 consecutive fp32 -> f16x8 (RN), A-fragment slice
__device__ __forceinline__ f16x8 lda(const float* p) {
  float4 a0 = *(const float4*)p, a1 = *(const float4*)(p + 4);
  f16x8 r;
  r[0] = (_Float16)a0.x; r[1] = (_Float16)a0.y; r[2] = (_Float16)a0.z; r[3] = (_Float16)a0.w;
  r[4] = (_Float16)a1.x; r[5] = (_Float16)a1.y; r[6] = (_Float16)a1.z; r[7] = (_Float16)a1.w;
  return r;
}

// Load this wave's 48 A-fragments of a [768][256] fp32 weight matrix (2 j-tiles x
// 3 gates x 8 k-chunks). A-layout (R13-verified): A[m=lane&15][k=(lane>>4)*8+i].
#define LOADWF(PTR)                                                                \
  { _Pragma("unroll") for (int ti = 0; ti < 2; ++ti) {                             \
      const int row = (w << 5) + (ti << 4) + nn;                                   \
      _Pragma("unroll") for (int kk = 0; kk < 8; ++kk) {                           \
        wfr[ti][kk] = lda((PTR) + (size_t)row * HDIM + kk * 32 + q * 8);           \
        wfz[ti][kk] = lda((PTR) + (size_t)(row + 256) * HDIM + kk * 32 + q * 8);   \
        wfn[ti][kk] = lda((PTR) + (size_t)(row + 512) * HDIM + kk * 32 + q * 8);   \
      } } }

// One recurrence matvec: G[768x16] = W * (hi + lo), 96 MFMA/wave.
// B-layout (R13-verified): B[k=(lane>>4)*8+i][n=lane&15]; hB is [n][k] so the
// per-lane read is 16B contiguous. D: [m=(lane>>4)*4+reg][n=lane&15].
#define MATVEC(PB)                                                                 \
  { _Pragma("unroll") for (int kk = 0; kk < 8; ++kk) {                             \
      const int ko = kk * 32 + q * 8;                                              \
      f16x8 bh = *(const f16x8*)&hBhi[PB][nn][ko];                                 \
      f16x8 bl = *(const f16x8*)&hBlo[PB][nn][ko];                                 \
      _Pragma("unroll") for (int ti = 0; ti < 2; ++ti) {                           \
        aR[ti] = __builtin_amdgcn_mfma_f32_16x16x32_f16(wfr[ti][kk], bh, aR[ti], 0, 0, 0); \
        aR[ti] = __builtin_amdgcn_mfma_f32_16x16x32_f16(wfr[ti][kk], bl, aR[ti], 0, 0, 0); \
        aZ[ti] = __builtin_amdgcn_mfma_f32_16x16x32_f16(wfz[ti][kk], bh, aZ[ti], 0, 0, 0); \
        aZ[ti] = __builtin_amdgcn_mfma_f32_16x16x32_f16(wfz[ti][kk], bl, aZ[ti], 0, 0, 0); \
        aN[ti] = __builtin_amdgcn_mfma_f32_16x16x32_f16(wfn[ti][kk], bh, aN[ti], 0, 0, 0); \
        aN[ti] = __builtin_amdgcn_mfma_f32_16x16x32_f16(wfn[ti][kk], bl, aN[ti], 0, 0, 0); \
      } } }

// write new h (4 rows, this lane's batch col) to the hi/lo B-layout buffers
#define HSTORE(PB1, TI, HNV)                                                       \
  { const int jb = (w << 5) + ((TI) << 4) + (q << 2);                              \
    __half2 h01 = __floats2half2_rn((HNV)[0], (HNV)[1]);                           \
    __half2 h23 = __floats2half2_rn((HNV)[2], (HNV)[3]);                           \
    float2 f01 = __half22float2(h01), f23 = __half22float2(h23);                   \
    __half2 l01 = __floats2half2_rn((HNV)[0] - f01.x, (HNV)[1] - f01.y);           \
    __half2 l23 = __floats2half2_rn((HNV)[2] - f23.x, (HNV)[3] - f23.y);           \
    uint2 uh = { __builtin_bit_cast(unsigned int, h01), __builtin_bit_cast(unsigned int, h23) }; \
    uint2 ul = { __builtin_bit_cast(unsigned int, l01), __builtin_bit_cast(unsigned int, l23) }; \
    *(uint2*)&hBhi[PB1][nn][jb] = uh;                                              \
    *(uint2*)&hBlo[PB1][nn][jb] = ul;                                              \
    uhs[TI] = uh; }

#define DECL_COMMON                                                                \
  const int tid = threadIdx.x;                                                     \
  const int w = tid >> 6, l = tid & 63, nn = l & 15, q = l >> 4;                   \
  const int b0 = blockIdx.x << 4;                                                  \
  f16x8 wfr[2][8], wfz[2][8], wfn[2][8];                                           \
  f32x4 aR[2], aZ[2], aN[2];                                                       \
  uint2 uhs[2];                                                                    \
  (void)uhs;

#define ZERO_HB                                                                    \
  for (int i = tid; i < 2112; i += 512) {                                          \
    ((unsigned int*)&hBhi[0][0][0])[i] = 0u;                                       \
    ((unsigned int*)&hBlo[0][0][0])[i] = 0u;                                       \
  }

#define ACC_ZERO                                                                   \
  aR[0] = (f32x4){0.f,0.f,0.f,0.f}; aR[1] = (f32x4){0.f,0.f,0.f,0.f};              \
  aZ[0] = (f32x4){0.f,0.f,0.f,0.f}; aZ[1] = (f32x4){0.f,0.f,0.f,0.f};              \
  aN[0] = (f32x4){0.f,0.f,0.f,0.f}; aN[1] = (f32x4){0.f,0.f,0.f,0.f};

// =========== Kernel 1: encoder GRU layer 0 (batched-16 MFMA recurrence) =======
__global__ __attribute__((amdgpu_flat_work_group_size(512, 512), amdgpu_waves_per_eu(2, 2)))
void gru_p1(const float* __restrict__ x,
            const float* __restrict__ Wih0, const float* __restrict__ Whh0,
            const float* __restrict__ bih0, const float* __restrict__ bhh0,
            __half* __restrict__ ys) {
  __shared__ alignas(16) __half hBhi[2][16][264];  // [buf][n][k + 8 pad]
  __shared__ alignas(16) __half hBlo[2][16][264];
  DECL_COMMON
  ZERO_HB
  LOADWF(Whh0);

  // per-lane scalar-path constants (4 j-rows per tile, this lane's q-slice)
  f32x4 wr4[2], wz4[2], wn4[2], cr4[2], cz4[2], bin4[2], bhn4[2];
#pragma unroll
  for (int ti = 0; ti < 2; ++ti) {
    const int jb = (w << 5) + (ti << 4) + (q << 2);
    wr4[ti] = *(const f32x4*)(Wih0 + jb);
    wz4[ti] = *(const f32x4*)(Wih0 + 256 + jb);
    wn4[ti] = *(const f32x4*)(Wih0 + 512 + jb);
    cr4[ti] = *(const f32x4*)(bih0 + jb) + *(const f32x4*)(bhh0 + jb);
    cz4[ti] = *(const f32x4*)(bih0 + 256 + jb) + *(const f32x4*)(bhh0 + 256 + jb);
    bin4[ti] = *(const f32x4*)(bih0 + 512 + jb);
    bhn4[ti] = *(const f32x4*)(bhh0 + 512 + jb);
  }
  f32x4 hfv[2] = {{0.f,0.f,0.f,0.f},{0.f,0.f,0.f,0.f}};  // exact f32 state (D-layout)
  const float* xrow = x + (size_t)(b0 + nn) * LSEQ;
  __syncthreads();

  int pb = 0;
#pragma unroll 1
  for (int t = 0; t < LSEQ; ++t) {
    const float xt = xrow[t];
    ACC_ZERO
    MATVEC(pb)
#pragma unroll
    for (int ti = 0; ti < 2; ++ti) {
      f32x4 hnv;
#pragma unroll
      for (int r = 0; r < 4; ++r) {
        const float rr = sigm(fmaf(xt, wr4[ti][r], cr4[ti][r]) + aR[ti][r]);
        const float zz = sigm(fmaf(xt, wz4[ti][r], cz4[ti][r]) + aZ[ti][r]);
        const float nv = tanh_(fmaf(rr, aN[ti][r] + bhn4[ti][r],
                                    fmaf(xt, wn4[ti][r], bin4[ti][r])));
        hnv[r] = fmaf(zz, hfv[ti][r] - nv, nv);
      }
      hfv[ti] = hnv;
      HSTORE(pb ^ 1, ti, hnv)
      const int jb = (w << 5) + (ti << 4) + (q << 2);
      *(uint2*)(ys + ((size_t)(b0 + nn) * LSEQ + t) * HDIM + jb) = uhs[ti];
    }
    pb ^= 1;
    __syncthreads();
  }
}

// ============ Kernel 2: GI1 = ys0 @ W_ih1^T + b_ih1 (R13-proven MFMA GEMM) ====
__global__ __launch_bounds__(256) void gemm_gi(
    const float* __restrict__ Wih1, const float* __restrict__ bih1,
    const __half* __restrict__ ys, __half* __restrict__ gi) {
  const int lane = threadIdx.x & 63;
  const int wv = threadIdx.x >> 6;
  const size_t bt0 = (size_t)blockIdx.x << 4;
  const int n = lane & 15, q = lane >> 4;

  f16x8 bfr[8];
  const __half* yrow = ys + (bt0 + n) * HDIM + q * 8;
#pragma unroll
  for (int kk = 0; kk < 8; ++kk) bfr[kk] = *(const f16x8*)(yrow + kk * 32);

#pragma unroll 1
  for (int mt = 0; mt < 12; ++mt) {
    const int j0 = (wv * 12 + mt) << 4;
    const float* arow = Wih1 + (size_t)(j0 + n) * HDIM + q * 8;
    f32x4 acc = {0.f, 0.f, 0.f, 0.f};
#pragma unroll
    for (int kk = 0; kk < 8; ++kk) {
      acc = __builtin_amdgcn_mfma_f32_16x16x32_f16(lda(arow + kk * 32), bfr[kk], acc, 0, 0, 0);
    }
    const int jr = j0 + (q << 2);
    __half o4[4];
#pragma unroll
    for (int r2 = 0; r2 < 4; ++r2) o4[r2] = __float2half(acc[r2] + bih1[jr + r2]);
    *(uint2*)(gi + (bt0 + n) * 768 + jr) = *(uint2*)o4;
  }
}

// ====== Kernel 3: encoder layer 1 + decoder (batched-16 MFMA recurrences) =====
__global__ __attribute__((amdgpu_flat_work_group_size(512, 512), amdgpu_waves_per_eu(2, 2)))
void gru_p34(const float* __restrict__ Whh1, const float* __restrict__ bhh1,
             const float* __restrict__ Wdih, const float* __restrict__ Wdhh,
             const float* __restrict__ bdih, const float* __restrict__ bdhh,
             const float* __restrict__ Wo, const float* __restrict__ bo,
             const __half* __restrict__ gi, float* __restrict__ out) {
  __shared__ alignas(16) __half hBhi[2][16][264];
  __shared__ alignas(16) __half hBlo[2][16][264];
  __shared__ float red[8][16];
  __shared__ float inp[16];
  DECL_COMMON
  ZERO_HB
  LOADWF(Whh1);

  f32x4 br4[2], bz4[2], bn4[2];
#pragma unroll
  for (int ti = 0; ti < 2; ++ti) {
    const int jb = (w << 5) + (ti << 4) + (q << 2);
    br4[ti] = *(const f32x4*)(bhh1 + jb);
    bz4[ti] = *(const f32x4*)(bhh1 + 256 + jb);
    bn4[ti] = *(const f32x4*)(bhh1 + 512 + jb);
  }
  f32x4 hfv[2] = {{0.f,0.f,0.f,0.f},{0.f,0.f,0.f,0.f}};
  __syncthreads();

  // ---------------- Phase 3: encoder GRU layer 1 ----------------
  int pb = 0;
#pragma unroll 1
  for (int t = 0; t < LSEQ; ++t) {
    const __half* gp = gi + ((size_t)(b0 + nn) * LSEQ + t) * 768;
    ushort4 gR[2], gZ[2], gN[2];
#pragma unroll
    for (int ti = 0; ti < 2; ++ti) {
      const int jb = (w << 5) + (ti << 4) + (q << 2);
      gR[ti] = *(const ushort4*)(gp + jb);
      gZ[ti] = *(const ushort4*)(gp + 256 + jb);
      gN[ti] = *(const ushort4*)(gp + 512 + jb);
    }
    ACC_ZERO
    MATVEC(pb)
#pragma unroll
    for (int ti = 0; ti < 2; ++ti) {
      const unsigned short grs[4] = {gR[ti].x, gR[ti].y, gR[ti].z, gR[ti].w};
      const unsigned short gzs[4] = {gZ[ti].x, gZ[ti].y, gZ[ti].z, gZ[ti].w};
      const unsigned short gns[4] = {gN[ti].x, gN[ti].y, gN[ti].z, gN[ti].w};
      f32x4 hnv;
#pragma unroll
      for (int r = 0; r < 4; ++r) {
        const float rr = sigm(__half2float(__builtin_bit_cast(__half, grs[r])) + aR[ti][r] + br4[ti][r]);
        const float zz = sigm(__half2float(__builtin_bit_cast(__half, gzs[r])) + aZ[ti][r] + bz4[ti][r]);
        const float nv = tanh_(fmaf(rr, aN[ti][r] + bn4[ti][r],
                                    __half2float(__builtin_bit_cast(__half, gns[r]))));
        hnv[r] = fmaf(zz, hfv[ti][r] - nv, nv);
      }
      hfv[ti] = hnv;
      HSTORE(pb ^ 1, ti, hnv)
    }
    pb ^= 1;
    __syncthreads();
  }

  // ---------------- Phase 4: autoregressive decoder ----------------
  LOADWF(Wdhh);
  f32x4 wr4[2], wz4[2], wn4[2], cr4[2], cz4[2], bin4[2], bhn4[2], wo4[2];
#pragma unroll
  for (int ti = 0; ti < 2; ++ti) {
    const int jb = (w << 5) + (ti << 4) + (q << 2);
    wr4[ti] = *(const f32x4*)(Wdih + jb);
    wz4[ti] = *(const f32x4*)(Wdih + 256 + jb);
    wn4[ti] = *(const f32x4*)(Wdih + 512 + jb);
    cr4[ti] = *(const f32x4*)(bdih + jb) + *(const f32x4*)(bdhh + jb);
    cz4[ti] = *(const f32x4*)(bdih + 256 + jb) + *(const f32x4*)(bdhh + 256 + jb);
    bin4[ti] = *(const f32x4*)(bdih + 512 + jb);
    bhn4[ti] = *(const f32x4*)(bdhh + 512 + jb);
    wo4[ti] = *(const f32x4*)(Wo + jb);
  }
  const float bov = bo[0];
  if (tid < 16) inp[tid] = 0.f;
  __syncthreads();

#pragma unroll 1
  for (int t = 0; t < PRED; ++t) {
    const float it = inp[nn];
    ACC_ZERO
    MATVEC(pb)
    float c = 0.f;
#pragma unroll
    for (int ti = 0; ti < 2; ++ti) {
      f32x4 hnv;
#pragma unroll
      for (int r = 0; r < 4; ++r) {
        const float rr = sigm(fmaf(it, wr4[ti][r], cr4[ti][r]) + aR[ti][r]);
        const float zz = sigm(fmaf(it, wz4[ti][r], cz4[ti][r]) + aZ[ti][r]);
        const float nv = tanh_(fmaf(rr, aN[ti][r] + bhn4[ti][r],
                                    fmaf(it, wn4[ti][r], bin4[ti][r])));
        hnv[r] = fmaf(zz, hfv[ti][r] - nv, nv);
        c = fmaf(wo4[ti][r], hnv[r], c);
      }
      hfv[ti] = hnv;
      HSTORE(pb ^ 1, ti, hnv)
    }
    c += __shfl_xor(c, 16);
    c += __shfl_xor(c, 32);
    if (l < 16) red[w][l] = c;
    __syncthreads();
    if (tid < 16) {
      float ov = bov;
#pragma unroll
      for (int ww = 0; ww < 8; ++ww) ov += red[ww][tid];
      out[(size_t)(b0 + tid) * PRED + t] = ov;
      inp[tid] = ov;
    }
    pb ^= 1;
    __syncthreads();
  }
}

extern "C" void kernel_launch(void* const* d_in, const int* in_sizes, int n_in,
                              void* d_out, int out_size, void* d_ws, size_t ws_size,
                              hipStream_t stream) {
  const float* x    = (const float*)d_in[0];
  const float* Wih0 = (const float*)d_in[1];
  const float* Whh0 = (const float*)d_in[2];
  const float* bih0 = (const float*)d_in[3];
  const float* bhh0 = (const float*)d_in[4];
  const float* Wih1 = (const float*)d_in[5];
  const float* Whh1 = (const float*)d_in[6];
  const float* bih1 = (const float*)d_in[7];
  const float* bhh1 = (const float*)d_in[8];
  const float* Wdih = (const float*)d_in[9];
  const float* Wdhh = (const float*)d_in[10];
  const float* bdih = (const float*)d_in[11];
  const float* bdhh = (const float*)d_in[12];
  const float* Wo   = (const float*)d_in[13];
  const float* bo   = (const float*)d_in[14];

  // ws layout: ys0 (f16, 64 MiB) | GI1 (f16, 192 MiB)
  __half* ys = (__half*)d_ws;
  __half* gi = ys + (size_t)256 * 512 * 256;

  gru_p1<<<16, 512, 0, stream>>>(x, Wih0, Whh0, bih0, bhh0, ys);
  gemm_gi<<<(256 * 512) / 16, 256, 0, stream>>>(Wih1, bih1, ys, gi);
  gru_p34<<<16, 512, 0, stream>>>(Whh1, bhh1, Wdih, Wdhh, bdih, bdhh, Wo, bo,
                                  gi, (float*)d_out);
}